// Round 1
// baseline (4305.313 us; speedup 1.0000x reference)
//
#include <hip/hip_runtime.h>

#define N_NODES 100000
#define N_EDGES 1600000
#define D_IN 128
#define HID 64
#define N_LAYERS 5
#define D_OUT 32
#define N_GRAPHS 1000

// ---------------------------------------------------------------------------
// Transpose GRU weights [192,64] -> [64,192] so that the GRU kernel's weight
// reads are lane-coalesced (lane = output feature j).
__global__ void k_transpose_gru(const float* __restrict__ w_ih,
                                const float* __restrict__ w_hh,
                                float* __restrict__ wT_ih,
                                float* __restrict__ wT_hh) {
    int t = blockIdx.x * blockDim.x + threadIdx.x;
    if (t >= 192 * 64) return;
    int r = t / 64, k = t % 64;          // r: row in [0,192), k: col in [0,64)
    wT_ih[k * 192 + r] = w_ih[r * 64 + k];
    wT_hh[k * 192 + r] = w_hh[r * 64 + k];
}

// ---------------------------------------------------------------------------
// x = node_embed @ W_in + b_in      [N,128] @ [128,64] -> [N,64]
// thread t -> (node n = t>>6, out feature j = t&63). Wave = one node row.
__global__ void k_input_linear(const float* __restrict__ ne,
                               const float* __restrict__ W_in,
                               const float* __restrict__ b_in,
                               float* __restrict__ h) {
    int t = blockIdx.x * blockDim.x + threadIdx.x;
    if (t >= N_NODES * HID) return;
    int n = t >> 6, j = t & 63;
    float acc = b_in[j];
    const float* nrow = ne + n * D_IN;
#pragma unroll 8
    for (int k = 0; k < D_IN; ++k)
        acc = fmaf(nrow[k], W_in[k * HID + j], acc);   // nrow[k]: wave-broadcast, W: coalesced
    h[t] = acc;
}

// ---------------------------------------------------------------------------
// m = h @ w_l                       [N,64] @ [64,64] -> [N,64]
__global__ void k_layer_matmul(const float* __restrict__ h,
                               const float* __restrict__ w,
                               float* __restrict__ m) {
    int t = blockIdx.x * blockDim.x + threadIdx.x;
    if (t >= N_NODES * HID) return;
    int n = t >> 6, j = t & 63;
    const float* hrow = h + n * HID;
    float acc = 0.0f;
#pragma unroll 8
    for (int k = 0; k < HID; ++k)
        acc = fmaf(hrow[k], w[k * HID + j], acc);
    m[t] = acc;
}

// ---------------------------------------------------------------------------
// agg[dst] += m[src] over all edges. One wave per edge, lane = feature.
// Reads/writes are contiguous 256B per wave; scatter via fp32 atomics.
__global__ void k_scatter(const int* __restrict__ ei,
                          const float* __restrict__ m,
                          float* __restrict__ agg) {
    int t = blockIdx.x * blockDim.x + threadIdx.x;
    if (t >= N_EDGES * HID) return;          // 102.4M < 2^31
    int e = t >> 6, lane = t & 63;
    int src = ei[e];
    int dst = ei[N_EDGES + e];
    atomicAdd(&agg[dst * HID + lane], m[src * HID + lane]);
}

// ---------------------------------------------------------------------------
// GRU cell (torch order r,z,n), in-place h update.
// gi = agg @ w_ih^T + b_ih ; gh = h @ w_hh^T + b_hh
__global__ void k_gru(const float* __restrict__ agg,
                      float* __restrict__ h,
                      const float* __restrict__ wT_ih,
                      const float* __restrict__ wT_hh,
                      const float* __restrict__ b_ih,
                      const float* __restrict__ b_hh) {
    int t = blockIdx.x * blockDim.x + threadIdx.x;
    if (t >= N_NODES * HID) return;
    int n = t >> 6, j = t & 63;
    const float* arow = agg + n * HID;
    const float* hrow = h + n * HID;

    float ir = b_ih[j],        iz = b_ih[64 + j],  inn = b_ih[128 + j];
    float hr = b_hh[j],        hz = b_hh[64 + j],  hnn = b_hh[128 + j];
#pragma unroll 4
    for (int k = 0; k < HID; ++k) {
        float a  = arow[k];                  // wave-broadcast
        float hv = hrow[k];                  // wave-broadcast
        const float* wi = wT_ih + k * 192;   // lane-coalesced (j = lane)
        const float* wh = wT_hh + k * 192;
        ir  = fmaf(a,  wi[j],       ir);
        iz  = fmaf(a,  wi[64 + j],  iz);
        inn = fmaf(a,  wi[128 + j], inn);
        hr  = fmaf(hv, wh[j],       hr);
        hz  = fmaf(hv, wh[64 + j],  hz);
        hnn = fmaf(hv, wh[128 + j], hnn);
    }
    float r = 1.0f / (1.0f + expf(-(ir + hr)));
    float z = 1.0f / (1.0f + expf(-(iz + hz)));
    float nn = tanhf(inn + r * hnn);
    float hold = hrow[j];
    // all lanes' loads precede this store in wave-lockstep program order
    h[t] = (1.0f - z) * nn + z * hold;
}

// ---------------------------------------------------------------------------
// Global mean-pool accumulation: sums[batch[n]] += h[n], cnt[batch[n]]++
__global__ void k_pool(const float* __restrict__ h,
                       const int* __restrict__ batch,
                       float* __restrict__ sums,
                       int* __restrict__ cnt) {
    int t = blockIdx.x * blockDim.x + threadIdx.x;
    if (t >= N_NODES * HID) return;
    int n = t >> 6, j = t & 63;
    int g = batch[n];
    atomicAdd(&sums[g * HID + j], h[t]);
    if (j == 0) atomicAdd(&cnt[g], 1);
}

// ---------------------------------------------------------------------------
// out = (sums/cnt) @ W_out + b_out        [G,64] @ [64,32] -> [G,32]
__global__ void k_out(const float* __restrict__ sums,
                      const int* __restrict__ cnt,
                      const float* __restrict__ W_out,
                      const float* __restrict__ b_out,
                      float* __restrict__ out) {
    int t = blockIdx.x * blockDim.x + threadIdx.x;
    if (t >= N_GRAPHS * D_OUT) return;
    int g = t / D_OUT, o = t % D_OUT;
    float inv_c = 1.0f / fmaxf((float)cnt[g], 1.0f);
    float acc = 0.0f;
#pragma unroll
    for (int k = 0; k < HID; ++k)
        acc = fmaf(sums[g * HID + k], W_out[k * D_OUT + o], acc);
    out[t] = acc * inv_c + b_out[o];
}

// ---------------------------------------------------------------------------
extern "C" void kernel_launch(void* const* d_in, const int* in_sizes, int n_in,
                              void* d_out, int out_size, void* d_ws, size_t ws_size,
                              hipStream_t stream) {
    const float* node_embed = (const float*)d_in[0];
    const int*   edge_index = (const int*)  d_in[1];
    const int*   batch      = (const int*)  d_in[2];
    const float* W_in       = (const float*)d_in[3];
    const float* b_in       = (const float*)d_in[4];
    const float* ggnn_w     = (const float*)d_in[5];
    const float* gru_w_ih   = (const float*)d_in[6];
    const float* gru_w_hh   = (const float*)d_in[7];
    const float* gru_b_ih   = (const float*)d_in[8];
    const float* gru_b_hh   = (const float*)d_in[9];
    const float* W_out      = (const float*)d_in[10];
    const float* b_out      = (const float*)d_in[11];
    float* out = (float*)d_out;

    // workspace layout (all 256B-aligned by construction)
    char* p = (char*)d_ws;
    float* h     = (float*)p; p += (size_t)N_NODES * HID * sizeof(float);   // 25.6 MB
    float* m     = (float*)p; p += (size_t)N_NODES * HID * sizeof(float);   // 25.6 MB
    float* agg   = (float*)p; p += (size_t)N_NODES * HID * sizeof(float);   // 25.6 MB
    float* wT_ih = (float*)p; p += 192 * 64 * sizeof(float);
    float* wT_hh = (float*)p; p += 192 * 64 * sizeof(float);
    float* sums  = (float*)p; p += (size_t)N_GRAPHS * HID * sizeof(float);
    int*   cnt   = (int*)  p; p += (size_t)N_GRAPHS * sizeof(int);

    const int BLK = 256;
    const int nodeThreads = N_NODES * HID;            // 6.4M
    const int nodeGrid    = (nodeThreads + BLK - 1) / BLK;
    const int edgeThreads = N_EDGES * HID;            // 102.4M
    const int edgeGrid    = (edgeThreads + BLK - 1) / BLK;

    k_transpose_gru<<<(192 * 64 + BLK - 1) / BLK, BLK, 0, stream>>>(gru_w_ih, gru_w_hh, wT_ih, wT_hh);
    k_input_linear<<<nodeGrid, BLK, 0, stream>>>(node_embed, W_in, b_in, h);

    for (int l = 0; l < N_LAYERS; ++l) {
        k_layer_matmul<<<nodeGrid, BLK, 0, stream>>>(h, ggnn_w + (size_t)l * HID * HID, m);
        hipMemsetAsync(agg, 0, (size_t)N_NODES * HID * sizeof(float), stream);
        k_scatter<<<edgeGrid, BLK, 0, stream>>>(edge_index, m, agg);
        k_gru<<<nodeGrid, BLK, 0, stream>>>(agg, h, wT_ih, wT_hh, gru_b_ih, gru_b_hh);
    }

    hipMemsetAsync(sums, 0, (size_t)N_GRAPHS * HID * sizeof(float), stream);
    hipMemsetAsync(cnt,  0, (size_t)N_GRAPHS * sizeof(int),        stream);
    k_pool<<<nodeGrid, BLK, 0, stream>>>(h, batch, sums, cnt);
    k_out<<<(N_GRAPHS * D_OUT + BLK - 1) / BLK, BLK, 0, stream>>>(sums, cnt, W_out, b_out, out);
}

// Round 2
// 1031.644 us; speedup vs baseline: 4.1733x; 4.1733x over previous
//
#include <hip/hip_runtime.h>

#define N_NODES 100000
#define N_EDGES 1600000
#define D_IN 128
#define HID 64
#define N_LAYERS 5
#define D_OUT 32
#define N_GRAPHS 1000

#define GRU_R 8          // nodes per thread
#define GRU_NB 32        // nodes per block (4 waves x 8)

__device__ __forceinline__ float fast_sigmoid(float x) {
    return __builtin_amdgcn_rcpf(1.0f + __expf(-x));
}
__device__ __forceinline__ float fast_tanh(float x) {
    // 1 - 2/(e^{2x}+1); handles +-inf correctly
    return 1.0f - 2.0f * __builtin_amdgcn_rcpf(1.0f + __expf(2.0f * x));
}

// ---------------------------------------------------------------------------
// Precompute combined weights:
//   Wc[l][k][j3] = sum_q ggnn_w[l][k][q] * gru_w_ih[j3][q]     ([64][192] per layer)
//   wT_hh[k][j3] = gru_w_hh[j3][k]                              ([64][192])
__global__ void k_prep(const float* __restrict__ ggnn_w,
                       const float* __restrict__ w_ih,
                       const float* __restrict__ w_hh,
                       float* __restrict__ Wc,
                       float* __restrict__ wT_hh) {
    int t = blockIdx.x * blockDim.x + threadIdx.x;
    const int NWC = N_LAYERS * HID * 192;           // 61440
    if (t < NWC) {
        int l = t / (HID * 192);
        int rem = t % (HID * 192);
        int k = rem / 192, j3 = rem % 192;
        const float* wl = ggnn_w + (size_t)l * HID * HID + (size_t)k * HID;
        const float* wi = w_ih + (size_t)j3 * HID;
        float acc = 0.0f;
#pragma unroll 8
        for (int q = 0; q < HID; ++q) acc = fmaf(wl[q], wi[q], acc);
        Wc[t] = acc;
    } else {
        int t2 = t - NWC;
        if (t2 < HID * 192) {
            int k = t2 / 192, j3 = t2 % 192;
            wT_hh[k * 192 + j3] = w_hh[(size_t)j3 * HID + k];
        }
    }
}

// ---------------------------------------------------------------------------
// CSR build: histogram of dst
__global__ void k_hist(const int* __restrict__ ei, int* __restrict__ deg) {
    int e = blockIdx.x * blockDim.x + threadIdx.x;
    if (e >= N_EDGES) return;
    atomicAdd(&deg[ei[N_EDGES + e]], 1);
}

// 3-kernel exclusive scan of deg[100000] -> off[100001]
#define SCHUNK 1024
__global__ __launch_bounds__(1024) void k_scan1(const int* __restrict__ deg,
                                                int* __restrict__ off,
                                                int* __restrict__ bsum) {
    __shared__ int buf[SCHUNK];
    int tid = threadIdx.x;
    int i = blockIdx.x * SCHUNK + tid;
    int v = (i < N_NODES) ? deg[i] : 0;
    buf[tid] = v;
    __syncthreads();
    for (int s = 1; s < SCHUNK; s <<= 1) {
        int a = (tid >= s) ? buf[tid - s] : 0;
        __syncthreads();
        buf[tid] += a;
        __syncthreads();
    }
    if (i < N_NODES) off[i] = buf[tid] - v;      // exclusive within chunk
    if (tid == SCHUNK - 1) bsum[blockIdx.x] = buf[tid];
}

__global__ void k_scan2(int* __restrict__ bsum, int* __restrict__ off, int nchunks) {
    // single thread: exclusive scan of chunk totals
    if (blockIdx.x == 0 && threadIdx.x == 0) {
        int carry = 0;
        for (int b = 0; b < nchunks; ++b) {
            int t = bsum[b];
            bsum[b] = carry;
            carry += t;
        }
        off[N_NODES] = carry;   // = N_EDGES
    }
}

__global__ void k_scan3(int* __restrict__ off, const int* __restrict__ bsum) {
    int i = blockIdx.x * blockDim.x + threadIdx.x;
    if (i < N_NODES) off[i] += bsum[i >> 10];
}

// place edges: csr_src[off[dst] + slot] = src
__global__ void k_place(const int* __restrict__ ei,
                        const int* __restrict__ off,
                        int* __restrict__ cur,
                        int* __restrict__ csr) {
    int e = blockIdx.x * blockDim.x + threadIdx.x;
    if (e >= N_EDGES) return;
    int d = ei[N_EDGES + e];
    int s = ei[e];
    int pos = off[d] + atomicAdd(&cur[d], 1);
    csr[pos] = s;
}

// ---------------------------------------------------------------------------
// x = node_embed @ W_in + b_in,  8 nodes/thread, rows staged in LDS
__global__ __launch_bounds__(256) void k_input(const float* __restrict__ ne,
                                               const float* __restrict__ W_in,
                                               const float* __restrict__ b_in,
                                               float* __restrict__ h) {
    __shared__ float sE[GRU_NB][D_IN];            // 16 KB
    int tid = threadIdx.x;
    int j = tid & 63, w = tid >> 6;
    int nodeBase = blockIdx.x * GRU_NB;
    {
        const float4* g = (const float4*)(ne + (size_t)nodeBase * D_IN);
        float4* l = (float4*)&sE[0][0];
        for (int i = tid; i < GRU_NB * D_IN / 4; i += 256) l[i] = g[i];
    }
    __syncthreads();
    float acc[GRU_R];
#pragma unroll
    for (int r = 0; r < GRU_R; ++r) acc[r] = 0.0f;
#pragma unroll 4
    for (int k = 0; k < D_IN; ++k) {
        float wv = W_in[k * HID + j];
#pragma unroll
        for (int r = 0; r < GRU_R; ++r)
            acc[r] = fmaf(sE[w * GRU_R + r][k], wv, acc[r]);
    }
    float b = b_in[j];
#pragma unroll
    for (int r = 0; r < GRU_R; ++r) {
        int n = nodeBase + w * GRU_R + r;
        h[(size_t)n * HID + j] = acc[r] + b;
    }
}

// ---------------------------------------------------------------------------
// agg0[n] = sum over in-edges of h[src]   (CSR gather, wave per node)
__global__ __launch_bounds__(256) void k_gather(const int* __restrict__ off,
                                                const int* __restrict__ csr,
                                                const float* __restrict__ h,
                                                float* __restrict__ agg0) {
    int t = blockIdx.x * blockDim.x + threadIdx.x;
    int n = t >> 6, j = t & 63;
    int beg = off[n], end = off[n + 1];
    float a0 = 0.f, a1 = 0.f, a2 = 0.f, a3 = 0.f;
    int i = beg;
    for (; i + 4 <= end; i += 4) {
        int s0 = csr[i], s1 = csr[i + 1], s2 = csr[i + 2], s3 = csr[i + 3];
        a0 += h[(size_t)s0 * HID + j];
        a1 += h[(size_t)s1 * HID + j];
        a2 += h[(size_t)s2 * HID + j];
        a3 += h[(size_t)s3 * HID + j];
    }
    for (; i < end; ++i) a0 += h[(size_t)csr[i] * HID + j];
    agg0[t] = (a0 + a1) + (a2 + a3);
}

// ---------------------------------------------------------------------------
// Fused matmul+GRU:  gi = agg0 @ Wc + b_ih ; gh = h @ wT_hh + b_hh ; h = GRU
__global__ __launch_bounds__(256) void k_gru(const float* __restrict__ agg0,
                                             float* __restrict__ h,
                                             const float* __restrict__ Wc,
                                             const float* __restrict__ wT_hh,
                                             const float* __restrict__ b_ih,
                                             const float* __restrict__ b_hh) {
    __shared__ float sA[GRU_NB][HID];             // 8 KB
    __shared__ float sH[GRU_NB][HID];             // 8 KB
    int tid = threadIdx.x;
    int j = tid & 63, w = tid >> 6;
    int nodeBase = blockIdx.x * GRU_NB;
    {
        const float4* gA = (const float4*)(agg0 + (size_t)nodeBase * HID);
        const float4* gH = (const float4*)(h + (size_t)nodeBase * HID);
        float4* lA = (float4*)&sA[0][0];
        float4* lH = (float4*)&sH[0][0];
        for (int i = tid; i < GRU_NB * HID / 4; i += 256) { lA[i] = gA[i]; lH[i] = gH[i]; }
    }
    __syncthreads();

    float air[GRU_R], aiz[GRU_R], ain[GRU_R];
    float ahr[GRU_R], ahz[GRU_R], ahn[GRU_R];
#pragma unroll
    for (int r = 0; r < GRU_R; ++r) {
        air[r] = 0.f; aiz[r] = 0.f; ain[r] = 0.f;
        ahr[r] = 0.f; ahz[r] = 0.f; ahn[r] = 0.f;
    }
#pragma unroll 2
    for (int k = 0; k < HID; ++k) {
        float wir = Wc[k * 192 + j];
        float wiz = Wc[k * 192 + 64 + j];
        float win = Wc[k * 192 + 128 + j];
        float whr = wT_hh[k * 192 + j];
        float whz = wT_hh[k * 192 + 64 + j];
        float whn = wT_hh[k * 192 + 128 + j];
#pragma unroll
        for (int r = 0; r < GRU_R; ++r) {
            float a = sA[w * GRU_R + r][k];
            float hv = sH[w * GRU_R + r][k];
            air[r] = fmaf(a, wir, air[r]);
            aiz[r] = fmaf(a, wiz, aiz[r]);
            ain[r] = fmaf(a, win, ain[r]);
            ahr[r] = fmaf(hv, whr, ahr[r]);
            ahz[r] = fmaf(hv, whz, ahz[r]);
            ahn[r] = fmaf(hv, whn, ahn[r]);
        }
    }
    float bir = b_ih[j], biz = b_ih[64 + j], bin_ = b_ih[128 + j];
    float bhr = b_hh[j], bhz = b_hh[64 + j], bhn = b_hh[128 + j];
#pragma unroll
    for (int r = 0; r < GRU_R; ++r) {
        int nn = w * GRU_R + r;
        float rr = fast_sigmoid((air[r] + bir) + (ahr[r] + bhr));
        float zz = fast_sigmoid((aiz[r] + biz) + (ahz[r] + bhz));
        float nv = fast_tanh((ain[r] + bin_) + rr * (ahn[r] + bhn));
        float hold = sH[nn][j];
        h[(size_t)(nodeBase + nn) * HID + j] = (1.0f - zz) * nv + zz * hold;
    }
}

// ---------------------------------------------------------------------------
// mean-pool accumulation exploiting sorted batch: register acc, flush on change
#define POOL_NPW 64
__global__ void k_pool(const float* __restrict__ h,
                       const int* __restrict__ batch,
                       float* __restrict__ sums,
                       float* __restrict__ cntf) {
    int wid = (blockIdx.x * blockDim.x + threadIdx.x) >> 6;
    int j = threadIdx.x & 63;
    int base = wid * POOL_NPW;
    if (base >= N_NODES) return;
    int end = base + POOL_NPW;
    if (end > N_NODES) end = N_NODES;
    float acc = 0.f, c = 0.f;
    int curg = batch[base];
    for (int n = base; n < end; ++n) {
        int g = batch[n];
        if (g != curg) {
            atomicAdd(&sums[(size_t)curg * HID + j], acc);
            if (j == 0) atomicAdd(&cntf[curg], c);
            acc = 0.f; c = 0.f; curg = g;
        }
        acc += h[(size_t)n * HID + j];
        c += 1.f;
    }
    atomicAdd(&sums[(size_t)curg * HID + j], acc);
    if (j == 0) atomicAdd(&cntf[curg], c);
}

// ---------------------------------------------------------------------------
__global__ void k_out(const float* __restrict__ sums,
                      const float* __restrict__ cntf,
                      const float* __restrict__ W_out,
                      const float* __restrict__ b_out,
                      float* __restrict__ out) {
    int t = blockIdx.x * blockDim.x + threadIdx.x;
    if (t >= N_GRAPHS * D_OUT) return;
    int g = t / D_OUT, o = t % D_OUT;
    float inv_c = __builtin_amdgcn_rcpf(fmaxf(cntf[g], 1.0f));
    float acc = 0.0f;
#pragma unroll
    for (int k = 0; k < HID; ++k)
        acc = fmaf(sums[g * HID + k], W_out[k * D_OUT + o], acc);
    out[t] = acc * inv_c + b_out[o];
}

// ---------------------------------------------------------------------------
static inline char* align256(char* p) {
    return (char*)(((uintptr_t)p + 255) & ~(uintptr_t)255);
}

extern "C" void kernel_launch(void* const* d_in, const int* in_sizes, int n_in,
                              void* d_out, int out_size, void* d_ws, size_t ws_size,
                              hipStream_t stream) {
    const float* node_embed = (const float*)d_in[0];
    const int*   edge_index = (const int*)  d_in[1];
    const int*   batch      = (const int*)  d_in[2];
    const float* W_in       = (const float*)d_in[3];
    const float* b_in       = (const float*)d_in[4];
    const float* ggnn_w     = (const float*)d_in[5];
    const float* gru_w_ih   = (const float*)d_in[6];
    const float* gru_w_hh   = (const float*)d_in[7];
    const float* gru_b_ih   = (const float*)d_in[8];
    const float* gru_b_hh   = (const float*)d_in[9];
    const float* W_out      = (const float*)d_in[10];
    const float* b_out      = (const float*)d_in[11];
    float* out = (float*)d_out;

    char* p = (char*)d_ws;
    float* h     = (float*)p; p = align256(p + (size_t)N_NODES * HID * sizeof(float));
    float* agg0  = (float*)p; p = align256(p + (size_t)N_NODES * HID * sizeof(float));
    int*   csr   = (int*)  p; p = align256(p + (size_t)N_EDGES * sizeof(int));
    int*   off   = (int*)  p; p = align256(p + (size_t)(N_NODES + 1) * sizeof(int));
    int*   deg   = (int*)  p; p = align256(p + (size_t)N_NODES * sizeof(int));
    int*   cur   = (int*)  p; p = align256(p + (size_t)N_NODES * sizeof(int));
    int*   bsum  = (int*)  p; p = align256(p + 256 * sizeof(int));
    float* Wc    = (float*)p; p = align256(p + (size_t)N_LAYERS * HID * 192 * sizeof(float));
    float* wT_hh = (float*)p; p = align256(p + (size_t)HID * 192 * sizeof(float));
    float* sums  = (float*)p;  // keep sums+cnt contiguous for a single memset
    float* cntf  = (float*)(p + (size_t)N_GRAPHS * HID * sizeof(float));

    const int BLK = 256;
    const int nchunks = (N_NODES + SCHUNK - 1) / SCHUNK;   // 98

    // --- weight prep (tiny) ---
    k_prep<<<(N_LAYERS * HID * 192 + HID * 192 + BLK - 1) / BLK, BLK, 0, stream>>>(
        ggnn_w, gru_w_ih, gru_w_hh, Wc, wT_hh);

    // --- CSR build ---
    hipMemsetAsync(deg, 0, (size_t)N_NODES * sizeof(int), stream);
    hipMemsetAsync(cur, 0, (size_t)N_NODES * sizeof(int), stream);
    k_hist<<<(N_EDGES + BLK - 1) / BLK, BLK, 0, stream>>>(edge_index, deg);
    k_scan1<<<nchunks, SCHUNK, 0, stream>>>(deg, off, bsum);
    k_scan2<<<1, 64, 0, stream>>>(bsum, off, nchunks);
    k_scan3<<<(N_NODES + BLK - 1) / BLK, BLK, 0, stream>>>(off, bsum);
    k_place<<<(N_EDGES + BLK - 1) / BLK, BLK, 0, stream>>>(edge_index, off, cur, csr);

    // --- input linear ---
    k_input<<<N_NODES / GRU_NB, BLK, 0, stream>>>(node_embed, W_in, b_in, h);

    // --- 5 GGNN layers ---
    for (int l = 0; l < N_LAYERS; ++l) {
        k_gather<<<N_NODES * HID / BLK, BLK, 0, stream>>>(off, csr, h, agg0);
        k_gru<<<N_NODES / GRU_NB, BLK, 0, stream>>>(
            agg0, h, Wc + (size_t)l * HID * 192, wT_hh, gru_b_ih, gru_b_hh);
    }

    // --- mean pool + output linear ---
    hipMemsetAsync(sums, 0, (size_t)N_GRAPHS * (HID + 1) * sizeof(float), stream);
    {
        int waves = (N_NODES + POOL_NPW - 1) / POOL_NPW;
        int threads = waves * 64;
        k_pool<<<(threads + BLK - 1) / BLK, BLK, 0, stream>>>(h, batch, sums, cntf);
    }
    k_out<<<(N_GRAPHS * D_OUT + BLK - 1) / BLK, BLK, 0, stream>>>(sums, cntf, W_out, b_out, out);
}